// Round 6
// baseline (137.696 us; speedup 1.0000x reference)
//
#include <hip/hip_runtime.h>

#define BB 131072
#define DD 512
#define NN 101
#define D4 128               // float4 per row
#define HALF 64              // float4 per half-row
#define NBLK 256             // one block per CU, all co-resident
#define BTHR 1024            // 16 waves
#define SPB 1024             // samples per block
#define NPAIR (NN * NN)      // 10201
#define PPB 80               // gram pairs per block (ceil(10201/128))

typedef float f4 __attribute__((ext_vector_type(4)));

// SINGLE dispatch. Blocks 0..127: feature-half 0; 128..255: half 1.
// Each block: stage ctr-half (103KB) + labels to LDS -> stream its 1024-sample
// emb slab (center MSE partial) -> 80 gram half-dots from LDS -> publish ->
// atomic arrival gate; the 256th arrival finalizes inline (margin + mean).
// Gate is mod-256: correct for ANY initial counter value (poison-proof),
// self-restoring, no memset dispatch needed.
__global__ __launch_bounds__(BTHR, 1) void fused_kernel(
    const f4* __restrict__ emb, const f4* __restrict__ ctr,
    const int* __restrict__ labels,
    float* __restrict__ partial,   // [NBLK]
    float* __restrict__ G0,        // [NPAIR] half-0 dots
    float* __restrict__ G1,        // [NPAIR] half-1 dots
    unsigned int* __restrict__ done,
    float* __restrict__ out)
{
    __shared__ f4  sctr[NN * HALF];   // 103424 B
    __shared__ int slab[SPB];         // 4096 B
    __shared__ float wsum[16];
    __shared__ unsigned int gate;
    __shared__ double dacc[4];
    __shared__ float denom[NN];
    __shared__ float mind[NN];
    __shared__ float wsum2[16];

    int b    = blockIdx.x;
    int h    = b >> 7;               // feature half
    int blk  = b & 127;              // block index within half
    int tid  = threadIdx.x;
    int wid  = tid >> 6;
    int lane = tid & 63;

    // ---- stage ctr half + labels into LDS ----
    for (int idx = tid; idx < NN * HALF; idx += BTHR)
        sctr[idx] = ctr[(idx >> 6) * D4 + h * HALF + (idx & 63)];
    slab[tid] = labels[blk * SPB + tid];
    __syncthreads();

    // ---- center (MSE) half-sums: 64 f4-loads/thread, unroll 4 ----
    float local = 0.f;
    const f4* base = emb + h * HALF + lane;
#pragma unroll 1
    for (int kk = 0; kk < 16; kk++) {
        int q0 = (kk * 4 + 0) * 16 + wid;
        int q1 = (kk * 4 + 1) * 16 + wid;
        int q2 = (kk * 4 + 2) * 16 + wid;
        int q3 = (kk * 4 + 3) * 16 + wid;
        int l0 = slab[q0];
        int l1 = slab[q1];
        int l2 = slab[q2];
        int l3 = slab[q3];
        f4 e0 = __builtin_nontemporal_load(base + (blk * SPB + q0) * D4);
        f4 e1 = __builtin_nontemporal_load(base + (blk * SPB + q1) * D4);
        f4 e2 = __builtin_nontemporal_load(base + (blk * SPB + q2) * D4);
        f4 e3 = __builtin_nontemporal_load(base + (blk * SPB + q3) * D4);
        f4 c0 = sctr[l0 * HALF + lane];
        f4 c1 = sctr[l1 * HALF + lane];
        f4 c2 = sctr[l2 * HALF + lane];
        f4 c3 = sctr[l3 * HALF + lane];
        f4 t0 = e0 - c0;
        f4 t1 = e1 - c1;
        f4 t2 = e2 - c2;
        f4 t3 = e3 - c3;
        local += t0.x * t0.x + t0.y * t0.y + t0.z * t0.z + t0.w * t0.w;
        local += t1.x * t1.x + t1.y * t1.y + t1.z * t1.z + t1.w * t1.w;
        local += t2.x * t2.x + t2.y * t2.y + t2.z * t2.z + t2.w * t2.w;
        local += t3.x * t3.x + t3.y * t3.y + t3.z * t3.z + t3.w * t3.w;
    }

    // ---- gram half-dots from LDS: 16 waves x 5 reps = 80 pairs ----
    float* Gh = h ? G1 : G0;
#pragma unroll
    for (int rep = 0; rep < 5; rep++) {
        int p = blk * PPB + rep * 16 + wid;
        if (p < NPAIR) {
            int i = p / NN;
            int j = p % NN;
            f4 a = sctr[i * HALF + lane];
            f4 c = sctr[j * HALF + lane];
            float dot = a.x * c.x + a.y * c.y + a.z * c.z + a.w * c.w;
            for (int off = 32; off > 0; off >>= 1)
                dot += __shfl_down(dot, off);
            if (lane == 0) Gh[p] = dot;
        }
    }

    // ---- block reduce -> partial[b] ----
    for (int off = 32; off > 0; off >>= 1)
        local += __shfl_down(local, off);
    if (lane == 0) wsum[wid] = local;
    __syncthreads();
    if (tid == 0) {
        float s = 0.f;
#pragma unroll
        for (int w = 0; w < 16; w++) s += wsum[w];
        partial[b] = s;
    }

    // ---- release + arrival gate (device scope; Guideline 16) ----
    __threadfence();                 // each thread releases its own stores
    __syncthreads();                 // all fences done before the atomic
    if (tid == 0) gate = atomicAdd(done, 1u) & 255u;
    __syncthreads();
    if (gate != 255u) return;        // block-uniform

    // ================= last-arriving block: finalize inline =================
    __threadfence();                 // acquire: see all other blocks' stores
    int t = tid;

    // center mean: sum 256 partials in double
    double dsum = (t < NBLK) ? (double)partial[t] : 0.0;
    for (int off = 32; off > 0; off >>= 1)
        dsum += __shfl_down(dsum, off);
    if (t < NBLK && (t & 63) == 0) dacc[t >> 6] = dsum;

    // margin: dist[i][j] = 1 - G/(max(sqrt(Gii),.1)*max(sqrt(Gjj),.1));
    // diag + |i-j|==1 masked before row-min; unmasked entries <= 2, so
    // skipping j in {t-1,t,t+1} is exactly equivalent.
    if (t < NN)
        denom[t] = fmaxf(sqrtf(G0[t * NN + t] + G1[t * NN + t]), 0.1f);
    __syncthreads();
    if (t < NN) {
        float di = denom[t];
        float mn = 1e30f;
        for (int j = 0; j < NN; j++) {
            if (j >= t - 1 && j <= t + 1) continue;
            float g = G0[t * NN + j] + G1[t * NN + j];
            mn = fminf(mn, 1.0f - g / (di * denom[j]));
        }
        mind[t] = mn;
    }
    __syncthreads();
    float contrib = 0.f;
    if (t >= 1 && t < NN) {          // d_lower[i]=dist[i][i-1] vs min_dist[1:]
        float g = G0[t * NN + (t - 1)] + G1[t * NN + (t - 1)];
        contrib += fmaxf(2.0f * (1.0f - g / (denom[t] * denom[t - 1])) - mind[t], 0.0f);
    }
    if (t < NN - 1) {                // d_upper[i]=dist[i][i+1] vs min_dist[:-1]
        float g = G0[t * NN + (t + 1)] + G1[t * NN + (t + 1)];
        contrib += fmaxf(2.0f * (1.0f - g / (denom[t] * denom[t + 1])) - mind[t], 0.0f);
    }
    for (int off = 32; off > 0; off >>= 1)
        contrib += __shfl_down(contrib, off);
    if ((t & 63) == 0) wsum2[t >> 6] = contrib;
    __syncthreads();
    if (t == 0) {
        float margin = 0.f;
#pragma unroll
        for (int w = 0; w < 16; w++) margin += wsum2[w];
        margin /= (float)NN;
        double center = (dacc[0] + dacc[1] + dacc[2] + dacc[3]) / (double)BB;
        out[0] = margin + (float)center;
    }
}

extern "C" void kernel_launch(void* const* d_in, const int* in_sizes, int n_in,
                              void* d_out, int out_size, void* d_ws, size_t ws_size,
                              hipStream_t stream) {
    const float* emb    = (const float*)d_in[0];
    const float* ctr    = (const float*)d_in[1];
    const int*   labels = (const int*)d_in[2];
    float* out = (float*)d_out;

    unsigned int* done = (unsigned int*)d_ws;                   // mod-256 gate (any init value OK)
    float* partial     = (float*)((char*)d_ws + 64);            // NBLK floats
    float* G0          = (float*)((char*)d_ws + 64 + NBLK * 4); // NPAIR floats
    float* G1          = G0 + NPAIR;                            // NPAIR floats

    fused_kernel<<<NBLK, BTHR, 0, stream>>>(
        (const f4*)emb, (const f4*)ctr, labels, partial, G0, G1, done, out);
}

// Round 7
// 76.703 us; speedup vs baseline: 1.7952x; 1.7952x over previous
//
#include <hip/hip_runtime.h>

#define BB 131072
#define DD 512
#define NN 101
#define D4 128                 // float4 per row
#define TOT (BB * D4)          // 16777216 float4 total
#define GBLK 256               // gram blocks (first in grid -> run during ramp)
#define CBLK 2048              // center blocks
#define STR (CBLK * 256)       // 524288 threads; TOT/STR = 32 iters exactly
#define NPAIR (NN * NN)        // 10201

typedef float f4 __attribute__((ext_vector_type(4)));

// Two dispatches, minimal work. Blocks 0..255: gram pair-dots (tiny, overlap
// the ramp). Blocks 256..2303: center MSE partial sums, fully contiguous emb
// stream (plain loads -> L3 may retain across graph replays), unroll-4 MLP.
__global__ __launch_bounds__(256, 8) void fused_kernel(
    const f4* __restrict__ emb, const f4* __restrict__ ctr,
    const int* __restrict__ labels,
    float* __restrict__ partial,   // [CBLK]
    float* __restrict__ G)         // [NPAIR]
{
    int lane = threadIdx.x & 63;
    int wid  = threadIdx.x >> 6;

    if (blockIdx.x < GBLK) {
        // ---- gram: one wave per (i,j) pair, grid-stride over 10201 pairs ----
        int w = blockIdx.x * 4 + wid;
        for (int p = w; p < NPAIR; p += GBLK * 4) {
            int i = p / NN;
            int j = p % NN;
            const f4* wi = ctr + i * D4;
            const f4* wj = ctr + j * D4;
            float dot = 0.f;
#pragma unroll
            for (int r = 0; r < 2; r++) {          // D4=128 = 64 lanes x 2
                f4 a = wi[lane + r * 64];
                f4 c = wj[lane + r * 64];
                dot += a.x * c.x + a.y * c.y + a.z * c.z + a.w * c.w;
            }
            for (int off = 32; off > 0; off >>= 1)
                dot += __shfl_down(dot, off);
            if (lane == 0) G[p] = dot;
        }
        return;
    }

    // ---- center (MSE) partial sums ----
    int b   = blockIdx.x - GBLK;
    int tid = b * 256 + threadIdx.x;
    int d4  = tid & (D4 - 1);          // STR multiple of 128 -> constant
    float local = 0.f;
#pragma unroll 1
    for (int kk = 0; kk < 8; kk++) {   // 32 iters = 8 x unroll-4
        int i0 = tid + (kk * 4 + 0) * STR;
        int i1 = tid + (kk * 4 + 1) * STR;
        int i2 = tid + (kk * 4 + 2) * STR;
        int i3 = tid + (kk * 4 + 3) * STR;
        int l0 = labels[i0 >> 7];      // wave-uniform -> scalar load
        int l1 = labels[i1 >> 7];
        int l2 = labels[i2 >> 7];
        int l3 = labels[i3 >> 7];
        f4 e0 = emb[i0];
        f4 e1 = emb[i1];
        f4 e2 = emb[i2];
        f4 e3 = emb[i3];
        f4 c0 = ctr[l0 * D4 + d4];     // L2-resident (207 KB, replicated per XCD)
        f4 c1 = ctr[l1 * D4 + d4];
        f4 c2 = ctr[l2 * D4 + d4];
        f4 c3 = ctr[l3 * D4 + d4];
        f4 t0 = e0 - c0;
        f4 t1 = e1 - c1;
        f4 t2 = e2 - c2;
        f4 t3 = e3 - c3;
        local += t0.x * t0.x + t0.y * t0.y + t0.z * t0.z + t0.w * t0.w;
        local += t1.x * t1.x + t1.y * t1.y + t1.z * t1.z + t1.w * t1.w;
        local += t2.x * t2.x + t2.y * t2.y + t2.z * t2.z + t2.w * t2.w;
        local += t3.x * t3.x + t3.y * t3.y + t3.z * t3.z + t3.w * t3.w;
    }
    for (int off = 32; off > 0; off >>= 1)
        local += __shfl_down(local, off);
    __shared__ float wsum[4];
    if (lane == 0) wsum[wid] = local;
    __syncthreads();
    if (threadIdx.x == 0)
        partial[b] = wsum[0] + wsum[1] + wsum[2] + wsum[3];
}

// ---------------- finalize: margin from G + center mean from partials ----------
// dist[i][j] = 1 - G[i][j]/(max(sqrt(G_ii),.1)*max(sqrt(G_jj),.1))
// diag + |i-j|==1 are +1e9-masked before the row min; unmasked entries <= 2,
// so skipping j in {t-1,t,t+1} is exactly equivalent.
__global__ __launch_bounds__(256) void finalize_kernel(
    const float* __restrict__ G, const float* __restrict__ partial,
    float* __restrict__ out)
{
    int t = threadIdx.x;

    double dsum = 0.0;
    for (int i = t; i < CBLK; i += 256)
        dsum += (double)partial[i];
    for (int off = 32; off > 0; off >>= 1)
        dsum += __shfl_down(dsum, off);
    __shared__ double dacc[4];
    if ((t & 63) == 0) dacc[t >> 6] = dsum;

    __shared__ float denom[NN];
    __shared__ float mind[NN];
    if (t < NN)
        denom[t] = fmaxf(sqrtf(G[t * NN + t]), 0.1f);
    __syncthreads();
    if (t < NN) {
        float di = denom[t];
        float mn = 1e30f;
        for (int j = 0; j < NN; j++) {
            if (j >= t - 1 && j <= t + 1) continue;
            float d = 1.0f - G[t * NN + j] / (di * denom[j]);
            mn = fminf(mn, d);
        }
        mind[t] = mn;
    }
    __syncthreads();
    float contrib = 0.f;
    if (t >= 1 && t < NN) {        // d_lower[i]=dist[i][i-1] vs min_dist[1:]
        float dl = 1.0f - G[t * NN + (t - 1)] / (denom[t] * denom[t - 1]);
        contrib += fmaxf(2.0f * dl - mind[t], 0.0f);
    }
    if (t < NN - 1) {              // d_upper[i]=dist[i][i+1] vs min_dist[:-1]
        float du = 1.0f - G[t * NN + (t + 1)] / (denom[t] * denom[t + 1]);
        contrib += fmaxf(2.0f * du - mind[t], 0.0f);
    }
    for (int off = 32; off > 0; off >>= 1)
        contrib += __shfl_down(contrib, off);
    __shared__ float wsum2[4];
    if ((t & 63) == 0) wsum2[t >> 6] = contrib;
    __syncthreads();
    if (t == 0) {
        float margin = (wsum2[0] + wsum2[1] + wsum2[2] + wsum2[3]) / (float)NN;
        double center = (dacc[0] + dacc[1] + dacc[2] + dacc[3]) / (double)BB;
        out[0] = margin + (float)center;
    }
}

extern "C" void kernel_launch(void* const* d_in, const int* in_sizes, int n_in,
                              void* d_out, int out_size, void* d_ws, size_t ws_size,
                              hipStream_t stream) {
    const float* emb    = (const float*)d_in[0];
    const float* ctr    = (const float*)d_in[1];
    const int*   labels = (const int*)d_in[2];
    float* out = (float*)d_out;

    float* partial = (float*)d_ws;                          // CBLK floats
    float* G       = (float*)((char*)d_ws + CBLK * 4);      // NPAIR floats
    // Every ws element used is unconditionally rewritten each call -> no memset.

    fused_kernel<<<GBLK + CBLK, 256, 0, stream>>>(
        (const f4*)emb, (const f4*)ctr, labels, partial, G);
    finalize_kernel<<<1, 256, 0, stream>>>(G, partial, out);
}